// Round 1
// 935.668 us; speedup vs baseline: 1.0015x; 1.0015x over previous
//
#include <hip/hip_runtime.h>

// EmbeddingSumConcat: B=4096 x F=32 bags, V=100000, L=20, E=64.
// One wave64 per (b,f) bag.
//
// Round-2 (prev): fully-unrolled 20x 1-row gathers (4B/lane), clamped
// over-length loads, 20 ds_bpermute on the address path, full vmcnt
// drain regardless of len -> ~420us kernel (inferred; top-5 rocprof
// rows are all 3.2GB harness poison fills at ~516us).
//
// Round-3: 4-rows-per-instruction gathers. Lane-group g = lane>>4 owns
// row l = 4r+g; each global_load_dwordx4 (16B/lane) fetches 4 rows
// (1KB). 5 bpermutes hoisted before the load block (one lgkmcnt wait),
// then up to 5 dwordx4 loads issued back-to-back; rounds with 4r >= len
// are skipped entirely via wave-uniform scalar branch (len is uniform
// per wave -> readfirstlane). Avg issued rounds = E[ceil(len/4)] = 2.9
// of 5; short bags retire early. Cross-group sum via shfl_xor(16,32);
// store = 16 lanes x dwordx4 (256B/wave, coalesced).

#define BB 4096
#define FF 32
#define VV 100000
#define LL 20
#define EE 64
#define NR 5   // rounds of 4 rows each

__global__ __launch_bounds__(256) void emb_bag_sum_kernel(
    const int* __restrict__ ids,      // [B, F, L] int32
    const int* __restrict__ lengths,  // [B, F]    int32
    const float* __restrict__ tables, // [F, V, E] f32
    float* __restrict__ out)          // [B, F*E]  f32
{
    const int wave = threadIdx.x >> 6;           // 4 waves per block
    const int lane = threadIdx.x & 63;
    const int bag  = (blockIdx.x << 2) + wave;   // bag = b*F + f
    const int f    = bag & (FF - 1);
    const int g    = lane >> 4;                  // row-group 0..3
    const int e4   = (lane & 15) << 2;           // element base 0,4,...,60

    const int len  = lengths[bag];               // wave-uniform in fact
    const int lenu = __builtin_amdgcn_readfirstlane(len);  // -> SGPR
    const int* __restrict__ idp = ids + bag * LL;          // fits int32
    const float* __restrict__ tab = tables + (size_t)f * (VV * EE);

    // Lanes 0..19 cooperatively load the 20 ids (one 80B coalesced load).
    int myid = (lane < LL) ? idp[lane] : 0;
    const int lastl = (lenu > 0) ? (lenu - 1) : 0;

    // All 5 round-ids up front: 5 bpermutes back-to-back, 1 lgkm wait.
    // Row for this lane in round r is l = 4r+g, clamped to lastl (ids[]
    // is fully populated with valid indices, so clamped reads are safe).
    int sid[NR];
#pragma unroll
    for (int r = 0; r < NR; ++r) {
        const int l  = 4 * r + g;
        const int sl = (l < lenu) ? l : lastl;
        sid[r] = __shfl(myid, sl);
    }

    // Gather: up to 5 dwordx4 loads, issued back-to-back, no waits
    // between (scalar branch per round only). Round r fetches rows
    // 4r..4r+3 (1KB per instruction).
    float4 v[NR];
#pragma unroll
    for (int r = 0; r < NR; ++r) {
        if (4 * r < lenu) {
            v[r] = *(const float4*)(tab + ((sid[r] << 6) + e4));
        }
    }

    // Masked accumulate (only boundary round has partially-valid rows).
    float4 acc = make_float4(0.0f, 0.0f, 0.0f, 0.0f);
#pragma unroll
    for (int r = 0; r < NR; ++r) {
        if (4 * r < lenu) {
            const bool m = (4 * r + g) < lenu;
            acc.x += m ? v[r].x : 0.0f;
            acc.y += m ? v[r].y : 0.0f;
            acc.z += m ? v[r].z : 0.0f;
            acc.w += m ? v[r].w : 0.0f;
        }
    }

    // Reduce across the 4 row-groups (lanes xor 16, then xor 32).
    acc.x += __shfl_xor(acc.x, 16); acc.y += __shfl_xor(acc.y, 16);
    acc.z += __shfl_xor(acc.z, 16); acc.w += __shfl_xor(acc.w, 16);
    acc.x += __shfl_xor(acc.x, 32); acc.y += __shfl_xor(acc.y, 32);
    acc.z += __shfl_xor(acc.z, 32); acc.w += __shfl_xor(acc.w, 32);

    // Lanes 0..15 store the 64-float output row (256B, coalesced).
    if (lane < 16) {
        *(float4*)(out + (size_t)bag * EE + e4) = acc;
    }
}

extern "C" void kernel_launch(void* const* d_in, const int* in_sizes, int n_in,
                              void* d_out, int out_size, void* d_ws, size_t ws_size,
                              hipStream_t stream) {
    const int*   ids     = (const int*)d_in[0];
    const int*   lengths = (const int*)d_in[1];
    const float* tables  = (const float*)d_in[2];
    float*       out     = (float*)d_out;

    const int n_bags = BB * FF;                  // 131072
    const int blocks = n_bags / 4;               // 4 bags (waves) per block
    emb_bag_sum_kernel<<<blocks, 256, 0, stream>>>(ids, lengths, tables, out);
}

// Round 2
// 929.033 us; speedup vs baseline: 1.0087x; 1.0071x over previous
//
#include <hip/hip_runtime.h>

// EmbeddingSumConcat: B=4096 x F=32 bags, V=100000, L=20, E=64.
// One wave64 per (b,f) bag.
//
// Round-3 post-mortem: cutting gather instrs 4x (20 -> ~2.9 VMEM/wave,
// early retire) changed dur_us by -0.15% (noise). With ~20k 256B rows
// in flight machine-wide and only 0.8 TB/s effective gather BW, the
// kernel is miss-path-bound (L2-MSHR occupancy x miss latency), not
// issue- or concurrency-bound.
//
// Round-4: f-major bag ordering. Old order (f fastest) means resident
// blocks spray all 32 tables (819 MB > 256 MB L3) at once, so the ~18%
// intra-f row repeats (40960 draws on 100k rows/f) miss L3 and pay full
// HBM latency. New order: flat = blockIdx*4+wave, f = flat/4096,
// b = flat%4096 -> the resident window sweeps ONE ~25.6 MB table at a
// time (fully L3-resident per phase). Repeats become L3 hits: -18% HBM
// fetch + lower avg miss latency -> higher MSHR-limited throughput.
// Output layout unchanged: out[bag] with bag = b*32+f.

#define BB 4096
#define FF 32
#define VV 100000
#define LL 20
#define EE 64
#define NR 5   // rounds of 4 rows each

__global__ __launch_bounds__(256) void emb_bag_sum_kernel(
    const int* __restrict__ ids,      // [B, F, L] int32
    const int* __restrict__ lengths,  // [B, F]    int32
    const float* __restrict__ tables, // [F, V, E] f32
    float* __restrict__ out)          // [B, F*E]  f32
{
    const int wave = threadIdx.x >> 6;           // 4 waves per block
    const int lane = threadIdx.x & 63;
    const int flat = (blockIdx.x << 2) + wave;   // 0..131071, f-major
    const int f    = flat >> 12;                 // flat / 4096
    const int b    = flat & (BB - 1);            // flat % 4096
    const int bag  = (b << 5) + f;               // b*32 + f (output order)
    const int g    = lane >> 4;                  // row-group 0..3
    const int e4   = (lane & 15) << 2;           // element base 0,4,...,60

    const int len  = lengths[bag];               // wave-uniform broadcast load
    const int lenu = __builtin_amdgcn_readfirstlane(len);  // -> SGPR
    const int* __restrict__ idp = ids + bag * LL;          // fits int32
    const float* __restrict__ tab = tables + (size_t)f * (VV * EE);

    // Lanes 0..19 cooperatively load the 20 ids (one 80B load).
    int myid = (lane < LL) ? idp[lane] : 0;
    const int lastl = (lenu > 0) ? (lenu - 1) : 0;

    // All 5 round-ids up front: 5 bpermutes back-to-back, 1 lgkm wait.
    // Row for this lane in round r is l = 4r+g, clamped to lastl (ids[]
    // is fully populated with valid indices, so clamped reads are safe).
    int sid[NR];
#pragma unroll
    for (int r = 0; r < NR; ++r) {
        const int l  = 4 * r + g;
        const int sl = (l < lenu) ? l : lastl;
        sid[r] = __shfl(myid, sl);
    }

    // Gather: up to 5 dwordx4 loads (1KB = 4 rows each), issued
    // back-to-back; rounds with 4r >= len skipped via scalar branch.
    float4 v[NR];
#pragma unroll
    for (int r = 0; r < NR; ++r) {
        if (4 * r < lenu) {
            v[r] = *(const float4*)(tab + ((sid[r] << 6) + e4));
        }
    }

    // Masked accumulate (only boundary round has partially-valid rows).
    float4 acc = make_float4(0.0f, 0.0f, 0.0f, 0.0f);
#pragma unroll
    for (int r = 0; r < NR; ++r) {
        if (4 * r < lenu) {
            const bool m = (4 * r + g) < lenu;
            acc.x += m ? v[r].x : 0.0f;
            acc.y += m ? v[r].y : 0.0f;
            acc.z += m ? v[r].z : 0.0f;
            acc.w += m ? v[r].w : 0.0f;
        }
    }

    // Reduce across the 4 row-groups (lanes xor 16, then xor 32).
    acc.x += __shfl_xor(acc.x, 16); acc.y += __shfl_xor(acc.y, 16);
    acc.z += __shfl_xor(acc.z, 16); acc.w += __shfl_xor(acc.w, 16);
    acc.x += __shfl_xor(acc.x, 32); acc.y += __shfl_xor(acc.y, 32);
    acc.z += __shfl_xor(acc.z, 32); acc.w += __shfl_xor(acc.w, 32);

    // Lanes 0..15 store the 64-float output row (256B, coalesced).
    if (lane < 16) {
        *(float4*)(out + (size_t)bag * EE + e4) = acc;
    }
}

extern "C" void kernel_launch(void* const* d_in, const int* in_sizes, int n_in,
                              void* d_out, int out_size, void* d_ws, size_t ws_size,
                              hipStream_t stream) {
    const int*   ids     = (const int*)d_in[0];
    const int*   lengths = (const int*)d_in[1];
    const float* tables  = (const float*)d_in[2];
    float*       out     = (float*)d_out;

    const int n_bags = BB * FF;                  // 131072
    const int blocks = n_bags / 4;               // 4 bags (waves) per block
    emb_bag_sum_kernel<<<blocks, 256, 0, stream>>>(ids, lengths, tables, out);
}